// Round 7
// baseline (282.277 us; speedup 1.0000x reference)
//
#include <hip/hip_runtime.h>
#include <cstddef>
#include <cstdint>

#define EMBED 1024
#define NH    16
#define DQ    64
#define NB    4
#define LSEQ  2048
#define MROWS (NB * LSEQ)   // 8192

typedef __bf16 bf16x8 __attribute__((ext_vector_type(8)));
typedef float  f32x4  __attribute__((ext_vector_type(4)));

// bf16 round-half-up: bias then take high 16. (RNE differs only on exact ties.)
__device__ __forceinline__ unsigned short f2bf(float f) {
    return (unsigned short)((__float_as_uint(f) + 0x8000u) >> 16);
}

// two floats -> packed bf16x2, round-half-up: 2 bias adds + 1 v_perm_b32.
__device__ __forceinline__ unsigned pack2(float a, float b) {
    unsigned ua = __float_as_uint(a) + 0x8000u;
    unsigned ub = __float_as_uint(b) + 0x8000u;
    return __builtin_amdgcn_perm(ub, ua, 0x07060302u);  // [b.hi16 : a.hi16]
}

__device__ __forceinline__ uint2 pack4(float a, float b, float c, float d) {
    return make_uint2(pack2(a, b), pack2(c, d));
}

// truncating pack (1 v_perm, no bias). Used for P where the bias cancels in
// the O = (P@V)/(P@1) ratio since l is computed from the same truncated P.
__device__ __forceinline__ unsigned pack2t(float a, float b) {
    return __builtin_amdgcn_perm(__float_as_uint(b), __float_as_uint(a), 0x07060302u);
}

// async global -> LDS, 16 B per lane. LDS dest = l + lane*16 (wave-uniform base l).
__device__ __forceinline__ void async_cp16(const void* g, void* l) {
    __builtin_amdgcn_global_load_lds((const __attribute__((address_space(1))) unsigned int*)g,
                                     (__attribute__((address_space(3))) unsigned int*)l,
                                     16, 0, 0);
}

// ---------------- phase skew ----------------
// Co-resident blocks run IDENTICAL per-tile loops with a barrier each tile
// and start simultaneously -> they stay phase-LOCKED: every wave on a SIMD
// wants the same pipe at the same instant (all QK-MFMA, then all exp2-VALU),
// so pipe times ADD instead of overlapping (flash: MfmaUtil 44 + VALUBusy 43,
// wall = sum ~5400cyc/tile vs max ~2800). A one-time per-block sleep of
// hash(block)&3 quarter-periods de-phases the residents; equal loop periods
// then preserve the skew. Cost <= ~4600 cyc of tail skew per kernel.
__device__ __forceinline__ void phase_skew(int sel) {
    for (int z = 0; z < sel; z++) {
        asm volatile("s_sleep 15" ::: "memory");   // ~960 cyc
        asm volatile("s_sleep 9"  ::: "memory");   // ~576 cyc
    }
}

// ---------------- prep: weight converts + transposed converts, ONE launch --
// grid (16,16,7): z 0..2 = transpose_cvt of Wq/Wk/Wv (64x64 tiles),
//                 z 3..6 = straight cvt of Wqp/Wkp/Wvp/Wout (grid-stride).
struct PrepArgs {
    const float* tsrc[3];
    unsigned short* tdst[3];
    const float* csrc[4];
    unsigned short* cdst[4];
};

__global__ __launch_bounds__(256) void prep_all(PrepArgs pa) {
    const int tid = threadIdx.x;
    if (blockIdx.z < 3) {
        __shared__ unsigned short Ts[64][68];
        const float* src = pa.tsrc[blockIdx.z];
        unsigned short* dst = pa.tdst[blockIdx.z];
        const int r0 = blockIdx.y * 64;
        const int c0 = blockIdx.x * 64;
        {
            int col4 = tid & 15;
            int rb   = tid >> 4;
#pragma unroll
            for (int it = 0; it < 4; it++) {
                int r = rb + it * 16;
                float4 f = *(const float4*)(src + (size_t)(r0 + r) * 1024 + c0 + col4 * 4);
                *(uint2*)&Ts[r][col4 * 4] = pack4(f.x, f.y, f.z, f.w);
            }
        }
        __syncthreads();
        {
            int oc = tid >> 2;
            int seg = tid & 3;
            __attribute__((aligned(16))) unsigned short tmp[16];
#pragma unroll
            for (int e = 0; e < 16; e++) tmp[e] = Ts[seg * 16 + e][oc];
            unsigned short* out = dst + (size_t)(c0 + oc) * 1024 + r0 + seg * 16;
            *(uint4*)(out)     = *(const uint4*)&tmp[0];
            *(uint4*)(out + 8) = *(const uint4*)&tmp[8];
        }
    } else {
        int job = blockIdx.z - 3;
        const float* s = pa.csrc[job];
        unsigned short* d = pa.cdst[job];
        const int n4 = (1024 * 1024) >> 2;
        int flat = blockIdx.y * 16 + blockIdx.x;            // 0..255
        for (int i = flat * 256 + tid; i < n4; i += 256 * 256) {
            float4 f = ((const float4*)s)[i];
            ((uint2*)d)[i] = pack4(f.x, f.y, f.z, f.w);
        }
    }
}

// ---------------- bf16 NT GEMM core: C = A(MxK) @ B(NxK)^T ----------------
// 128x128 tile, BK=64 (32 KB LDS, 32 MFMA per barrier pair), 256 threads =
// 4 waves, each wave a 64x64 quadrant of 4x4 mfma_f32_16x16x32_bf16.
// Staging via global_load_lds w=16 with xor chunk swizzle:
//   LDS chunk c (16B) holds global (row r=c>>3, k-chunk (c&7)^(r&7)).
// XCD-chunked block swizzle (per-z nwg is a multiple of 8 in all our
// launches -> bijective): the 8 blocks sharing one A row-panel land on ONE
// XCD's L2 instead of 8, cutting A re-fetch ~8x.
//
// Callers use __launch_bounds__(256, 4): gfx950 has a UNIFIED VGPR/AGPR
// file; default allocation was 88 VGPR + 64 AGPR = 152 -> (128,256] bin ->
// 2 blocks/CU -> MfmaUtil 27%. Forcing 4 waves/EU fits VGPR+AGPR <= 128
// -> 4 blocks/CU (R5: projection 76 -> ~58 us).
//
// mode: 0 = bf16 row-major (acc*scl), 1 = fp32 row-major,
// mode 2 = bf16 C^T (ld=M) with KEY-PERMUTED rows for the flash PV B-layout:
//   within each 32-row group, row 16h+4g+e  is stored at  8g+4h+e.
//   (PV contracts V^T and P^T over the same permuted index; permutation
//   applied identically to both operands leaves the product unchanged.)
//   Transposes through LDS so global writes stay 8B-unit contiguous runs.
struct BGemmArgs {
    const unsigned short* A[3];
    const unsigned short* B[3];
    void* C[3];
    int mode[3];
    float scl[3];
};

__device__ __forceinline__ void gemm_core(const BGemmArgs& p, int M, int N, int K,
                                          unsigned short* SMEM) {
    unsigned short* As = SMEM;
    unsigned short* Bs = SMEM + 128 * 64;

    const int tid  = threadIdx.x;
    const int wave = tid >> 6;
    const int lane = tid & 63;
    const int m16  = lane & 15;
    const int kq   = lane >> 4;

    // XCD swizzle within the z-slice (nwg % 8 == 0 for all our grids).
    const int nwg  = gridDim.x * gridDim.y;
    const int flat = blockIdx.y * gridDim.x + blockIdx.x;
    const int swz  = (flat & 7) * (nwg >> 3) + (flat >> 3);
    const int bm = (swz / gridDim.x) * 128;
    const int bn = (swz % gridDim.x) * 128;
    const int z  = blockIdx.z;
    const unsigned short* A = p.A[z];
    const unsigned short* B = p.B[z];

    // de-phase co-resident blocks (see phase_skew comment)
    phase_skew((flat ^ (flat >> 2) ^ (flat >> 5)) & 3);

    f32x4 acc[4][4];
#pragma unroll
    for (int i = 0; i < 4; i++)
#pragma unroll
        for (int j = 0; j < 4; j++) acc[i][j] = f32x4{0.f, 0.f, 0.f, 0.f};

    const int wr = (wave >> 1) * 64;
    const int wc = (wave & 1) * 64;

    for (int k0 = 0; k0 < K; k0 += 64) {
#pragma unroll
        for (int it = 0; it < 4; it++) {
            int c = tid + it * 256;         // chunk 0..1023
            int r = c >> 3;                 // tile row 0..127
            int kc = (c & 7) ^ (r & 7);     // swizzled k-chunk in row
            async_cp16(A + (size_t)(bm + r) * K + k0 + kc * 8,
                       &As[(it * 256 + wave * 64) * 8]);
            async_cp16(B + (size_t)(bn + r) * K + k0 + kc * 8,
                       &Bs[(it * 256 + wave * 64) * 8]);
        }
        __syncthreads();

#pragma unroll
        for (int s = 0; s < 2; s++) {
            bf16x8 af[4], bfr[4];
#pragma unroll
            for (int i = 0; i < 4; i++) {
                int ra = wr + i * 16 + m16;
                af[i] = *reinterpret_cast<const bf16x8*>(
                    &As[ra * 64 + (((s * 4 + kq) ^ (ra & 7)) * 8)]);
                int rb = wc + i * 16 + m16;
                bfr[i] = *reinterpret_cast<const bf16x8*>(
                    &Bs[rb * 64 + (((s * 4 + kq) ^ (rb & 7)) * 8)]);
            }
#pragma unroll
            for (int i = 0; i < 4; i++)
#pragma unroll
                for (int j = 0; j < 4; j++)
                    acc[i][j] = __builtin_amdgcn_mfma_f32_16x16x32_bf16(af[i], bfr[j], acc[i][j], 0, 0, 0);
        }
        __syncthreads();
    }

    const int mode = p.mode[z];
    const float scl = p.scl[z];
    if (mode == 0) {
        unsigned short* Cb = (unsigned short*)p.C[z];
#pragma unroll
        for (int i = 0; i < 4; i++)
#pragma unroll
            for (int j = 0; j < 4; j++) {
                int row = bm + wr + i * 16 + kq * 4;
                int col = bn + wc + j * 16 + m16;
#pragma unroll
                for (int q = 0; q < 4; q++)
                    Cb[(size_t)(row + q) * N + col] = f2bf(acc[i][j][q] * scl);
            }
    } else if (mode == 1) {
        float* Cf = (float*)p.C[z];
#pragma unroll
        for (int i = 0; i < 4; i++)
#pragma unroll
            for (int j = 0; j < 4; j++) {
                int row = bm + wr + i * 16 + kq * 4;
                int col = bn + wc + j * 16 + m16;
#pragma unroll
                for (int q = 0; q < 4; q++)
                    Cf[(size_t)(row + q) * N + col] = acc[i][j][q];
            }
    } else {
        // C^T through LDS. Last loop iteration ended with __syncthreads(),
        // so As/Bs are free to reuse as the 128x128 bf16 transpose buffer.
        // Layout: Tt[col][row-unit], row-unit = 4 rows (8 B). Add-rotate
        // swizzle u' = (u + 2*col) & 31 spreads banks (<=2-way conflicts)
        // with zero padding, so the buffer is exactly 32 KB.
        unsigned short* Tt = SMEM;
#pragma unroll
        for (int i = 0; i < 4; i++)
#pragma unroll
            for (int j = 0; j < 4; j++) {
                int c = wc + j * 16 + m16;          // local col 0..127 (N-dim)
                int u = (wr >> 2) + i * 4 + kq;     // row unit 0..31 (M-dim/4)
                int us = (u + 2 * c) & 31;
                *reinterpret_cast<uint2*>(&Tt[c * 128 + us * 4]) =
                    pack4(acc[i][j][0], acc[i][j][1], acc[i][j][2], acc[i][j][3]);
            }
        __syncthreads();
        unsigned short* Ct = (unsigned short*)p.C[z];
        int r8 = tid & 15;          // 8-row chunk within tile
        int cb = tid >> 4;          // col offset within pass
#pragma unroll
        for (int pass = 0; pass < 8; pass++) {
            int c  = pass * 16 + cb;
            int u0 = r8 * 2;                       // even -> us,us+1 contiguous
            int us = (u0 + 2 * c) & 31;
            uint4 val = *reinterpret_cast<const uint4*>(&Tt[c * 128 + us * 4]);
            // Key-permuted write: rows key0..key0+7 split into two 4-row
            // (8 B) units at permuted positions p = 8g + 4h + e (h = bit4,
            // g = bits3:2 of the local-32 row index). dst1 = dst0 + 8.
            int key0 = r8 * 8;                     // local row base, step 8
            int loc  = key0 & 31;                  // 0, 8, 16, 24
            int dst0 = (key0 & 96) + (((loc & 15) >> 2) * 8) + ((loc >> 4) * 4);
            unsigned short* out = &Ct[(size_t)(bn + c) * M + bm + dst0];
            *reinterpret_cast<uint2*>(out)     = make_uint2(val.x, val.y);
            *reinterpret_cast<uint2*>(out + 8) = make_uint2(val.z, val.w);
        }
    }
}

__global__ __launch_bounds__(256, 4) void gemm_bf16nt(BGemmArgs p, int M, int N, int K) {
    __shared__ __align__(16) unsigned short SMEM[2 * 128 * 64];
    gemm_core(p, M, N, K, SMEM);
}

// ---------------- fusion GEMM + x-convert, ONE launch ----------------
// z 0..2 = weight-fusion GEMM, z 3..5 = x fp32->bf16 cvt on the idle CUs.
struct FuseXArgs {
    BGemmArgs g;
    const float* xsrc;
    unsigned short* xdst;
};

__global__ __launch_bounds__(256, 4) void gemm_fuse_xcvt(FuseXArgs fa) {
    if (blockIdx.z < 3) {
        __shared__ __align__(16) unsigned short SMEM[2 * 128 * 64];
        gemm_core(fa.g, 1024, 1024, 1024, SMEM);
    } else {
        const int n4 = (MROWS * EMBED) >> 2;              // 2,097,152 float4
        int slice = blockIdx.z - 3;
        int flat  = blockIdx.y * gridDim.x + blockIdx.x;  // 0..63
        int start = (slice * 64 + flat) * 256 + threadIdx.x;
        const float4* s = (const float4*)fa.xsrc;
        uint2* d = (uint2*)fa.xdst;
        for (int i = start; i < n4; i += 192 * 256) {
            float4 f = s[i];
            d[i] = pack4(f.x, f.y, f.z, f.w);
        }
    }
}

// ---------------- flash attention, bf16 MFMA, no-max softmax ----------------
// Q is pre-scaled by 0.125*log2(e) in the projection GEMM epilogue, so
//   p = exp2(k.q_scaled) == exp(q.k/8)  (|q.k/8| <~ 2 -> no-max is safe).
// Row-sum l is folded into the PV stage: extra MFMAs with an all-ones
// A-fragment compute column sums of P^T; in the C/D layout every lane then
// holds l for its own q-column in all regs -> no adds, no shuffles.
// P is packed to bf16 by TRUNCATION; bias cancels in O = (P@V)/(P@1).
// Orientation: St = K @ Q^T (m=key, n=qrow), O^T = V^T @ P^T (m=d, n=qrow).
// Block: 128 q-rows, 4 waves, wave owns 32 q-rows. Key-tile 64. Grid 1024.
//
// v7: phase_skew de-phases the 4 co-resident blocks (lockstep diagnosis:
//     MfmaUtil 44 + VALUBusy 43 with wall = SUM of pipe demands, and R6's
//     VALU-trim was neutral -> issue slots weren't the limit, phase overlap
//     was). Keeps v5/v6: key-permuted zero-shuffle PV at K=32, Pt LDS
//     deleted (bank conflicts 0), K/V dbuf 32 KB, stage(next) at iter top +
//     single vmcnt(0)+s_barrier at iter end, T5 setprio, XCD swizzle,
//     shared zero4 C-in.
__global__ __launch_bounds__(256, 4)
void flash_bf16(const unsigned short* __restrict__ qb,
                const unsigned short* __restrict__ kb,
                const unsigned short* __restrict__ vtb,
                unsigned short* __restrict__ ao) {
    __shared__ __align__(16) unsigned short Ks[2][64 * 64];
    __shared__ __align__(16) unsigned short Vt[2][64 * 64];

    const int tid  = threadIdx.x;
    const int wave = tid >> 6;
    const int lane = tid & 63;
    const int m16  = lane & 15;
    const int kq   = lane >> 4;

    // XCD swizzle: linear dispatch id -> 128-contiguous chunk per XCD.
    const int flat = blockIdx.y * (LSEQ / 128) + blockIdx.x;   // 0..1023
    const int swz  = (flat & 7) * 128 + (flat >> 3);
    const int bh   = swz >> 4;               // 0..63
    const int nn   = bh >> 4;                // batch
    const int h    = bh & 15;                // head
    const int q0   = (swz & 15) * 128;       // query tile base

    // all-ones A-fragment (bf16 1.0 = 0x3F80) for the l-row MFMAs
    const uint4 ones_u = make_uint4(0x3F803F80u, 0x3F803F80u, 0x3F803F80u, 0x3F803F80u);
    const bf16x8 ones8 = __builtin_bit_cast(bf16x8, ones_u);

    const unsigned short* kptr  = kb + (size_t)(nn * LSEQ) * EMBED + h * DQ;
    const unsigned short* vtptr = vtb + (size_t)(h * DQ) * MROWS + nn * LSEQ;

    auto stage = [&](int buf) {
#pragma unroll
        for (int it = 0; it < 2; it++) {
            int c = tid + it * 256;            // chunk 0..511
            int r = c >> 3;                    // row 0..63
            int kc = (c & 7) ^ (r & 7);        // swizzled chunk in row
            async_cp16(kptr + (size_t)r * EMBED + kc * 8,
                       &Ks[buf][(it * 256 + wave * 64) * 8]);
            async_cp16(vtptr + (size_t)r * MROWS + kc * 8,
                       &Vt[buf][(it * 256 + wave * 64) * 8]);
        }
        kptr  += 64 * EMBED;
        vtptr += 64;
    };

    // prologue: stage tile 0; Q fragment loads overlap the staging.
    stage(0);

    // Q fragments: qf[j][s] = Q[q0+wave*32+j*16+m16][s*32 + kq*8 .. +7]
    bf16x8 qf[2][2];
#pragma unroll
    for (int j = 0; j < 2; j++) {
        size_t tok = (size_t)(nn * LSEQ + q0 + wave * 32 + j * 16 + m16);
#pragma unroll
        for (int s = 0; s < 2; s++)
            qf[j][s] = *reinterpret_cast<const bf16x8*>(
                &qb[tok * EMBED + h * DQ + s * 32 + kq * 8]);
    }

    f32x4 o[4][2];   // o[mt][j]: O^T tile (d = mt*16+kq*4+reg, qcol = j*16+m16)
    f32x4 o4[2];     // l accumulator (all regs equal per lane)
#pragma unroll
    for (int j = 0; j < 2; j++) {
        o4[j] = f32x4{0.f, 0.f, 0.f, 0.f};
#pragma unroll
        for (int mt = 0; mt < 4; mt++) o[mt][j] = f32x4{0.f, 0.f, 0.f, 0.f};
    }
    const f32x4 zero4 = f32x4{0.f, 0.f, 0.f, 0.f};   // shared MFMA C-in

    asm volatile("s_waitcnt vmcnt(0)" ::: "memory");   // tile 0 + Q landed
    __builtin_amdgcn_s_barrier();
    asm volatile("" ::: "memory");

    // de-phase co-resident blocks (tile 0 already in LDS; sleep costs
    // nothing correctness-wise, buys pipe overlap across blocks)
    phase_skew((flat ^ (flat >> 2) ^ (flat >> 5)) & 3);

    const int NT = LSEQ / 64;    // 32
    for (int kt = 0; kt < NT; kt++) {
        const int cur = kt & 1;
        if (kt + 1 < NT) stage(cur ^ 1);   // prefetch next tile (no wait)

        // St = K @ Q^T : st[i][j], key = i*16+kq*4+reg, qcol = j*16+m16.
        // s=0 feeds the shared zero4 as C-in (no per-tile zero-init loop).
        f32x4 st[4][2];
#pragma unroll
        for (int s = 0; s < 2; s++) {
            bf16x8 ak[4];
#pragma unroll
            for (int i = 0; i < 4; i++) {
                int key = i * 16 + m16;
                ak[i] = *reinterpret_cast<const bf16x8*>(
                    &Ks[cur][key * 64 + (((s * 4 + kq) ^ (m16 & 7)) * 8)]);
            }
            __builtin_amdgcn_s_setprio(1);
            if (s == 0) {
#pragma unroll
                for (int i = 0; i < 4; i++)
#pragma unroll
                    for (int j = 0; j < 2; j++)
                        st[i][j] = __builtin_amdgcn_mfma_f32_16x16x32_bf16(ak[i], qf[j][0], zero4, 0, 0, 0);
            } else {
#pragma unroll
                for (int i = 0; i < 4; i++)
#pragma unroll
                    for (int j = 0; j < 2; j++)
                        st[i][j] = __builtin_amdgcn_mfma_f32_16x16x32_bf16(ak[i], qf[j][1], st[i][j], 0, 0, 0);
            }
            __builtin_amdgcn_s_setprio(0);
        }

        // PV over two 32-key chunks t. V^T fragment: one b128 per (t,mt)
        // (vtbuf keys pre-permuted to the K=32 slot map k=8kq+e).
        // P fragment: pb[j] slots e<4 = st[2t][j][e], e>=4 = st[2t+1][j][e-4].
#pragma unroll
        for (int t = 0; t < 2; t++) {
            bf16x8 av8[4];
#pragma unroll
            for (int mt = 0; mt < 4; mt++) {
                int d = mt * 16 + m16;
                av8[mt] = *reinterpret_cast<const bf16x8*>(
                    &Vt[cur][d * 64 + (((t * 4 + kq) ^ (m16 & 7)) * 8)]);
            }
            // p = exp2(st) for key-blocks 2t, 2t+1 (Q pre-scaled)
#pragma unroll
            for (int ii = 0; ii < 2; ii++)
#pragma unroll
                for (int j = 0; j < 2; j++)
#pragma unroll
                    for (int q = 0; q < 4; q++)
                        st[2 * t + ii][j][q] = __builtin_amdgcn_exp2f(st[2 * t + ii][j][q]);
            bf16x8 pb[2];
#pragma unroll
            for (int j = 0; j < 2; j++) {
                uint4 pu;
                pu.x = pack2t(st[2 * t][j][0],     st[2 * t][j][1]);
                pu.y = pack2t(st[2 * t][j][2],     st[2 * t][j][3]);
                pu.z = pack2t(st[2 * t + 1][j][0], st[2 * t + 1][j][1]);
                pu.w = pack2t(st[2 * t + 1][j][2], st[2 * t + 1][j][3]);
                pb[j] = __builtin_bit_cast(bf16x8, pu);
            }
            __builtin_amdgcn_s_setprio(1);
#pragma unroll
            for (int mt = 0; mt < 4; mt++)
#pragma unroll
                for (int j = 0; j < 2; j++)
                    o[mt][j] = __builtin_amdgcn_mfma_f32_16x16x32_bf16(av8[mt], pb[j], o[mt][j], 0, 0, 0);
#pragma unroll
            for (int j = 0; j < 2; j++)
                o4[j] = __builtin_amdgcn_mfma_f32_16x16x32_bf16(ones8, pb[j], o4[j], 0, 0, 0);
            __builtin_amdgcn_s_setprio(0);
        }

        // Release buf[cur] for next iter's stage; next tile's loads (issued
        // at iter top) drained here, hidden under the compute above.
        if (kt + 1 < NT) {
            asm volatile("s_waitcnt vmcnt(0)" ::: "memory");
            __builtin_amdgcn_s_barrier();
            asm volatile("" ::: "memory");
        }
    }

    // Epilogue: normalize by l (= o4[j][0], identical in all regs), write ao.
#pragma unroll
    for (int j = 0; j < 2; j++) {
        float inv = 1.f / o4[j][0];
        size_t tok = (size_t)(nn * LSEQ + q0 + wave * 32 + j * 16 + m16);
#pragma unroll
        for (int mt = 0; mt < 4; mt++) {
            *reinterpret_cast<uint2*>(&ao[tok * EMBED + h * DQ + mt * 16 + kq * 4]) =
                pack4(o[mt][j][0] * inv, o[mt][j][1] * inv, o[mt][j][2] * inv, o[mt][j][3] * inv);
        }
    }
}

// ---------------- host ----------------
extern "C" void kernel_launch(void* const* d_in, const int* in_sizes, int n_in,
                              void* d_out, int out_size, void* d_ws, size_t ws_size,
                              hipStream_t stream) {
    (void)in_sizes; (void)n_in; (void)out_size; (void)ws_size;
    const float* x     = (const float*)d_in[0];
    const float* W_q   = (const float*)d_in[1];
    const float* W_k   = (const float*)d_in[2];
    const float* W_v   = (const float*)d_in[3];
    const float* W_qp  = (const float*)d_in[4];
    const float* W_kp  = (const float*)d_in[5];
    const float* W_vp  = (const float*)d_in[6];
    const float* W_out = (const float*)d_in[7];

    unsigned short* ws16 = (unsigned short*)d_ws;
    const size_t SZX = (size_t)MROWS * EMBED;   // 8,388,608
    const size_t SZW = (size_t)EMBED * EMBED;   // 1,048,576

    unsigned short* xb    = ws16;
    unsigned short* wqpb  = xb + SZX;
    unsigned short* wkpb  = wqpb + SZW;
    unsigned short* wvpb  = wkpb + SZW;
    unsigned short* woutb = wvpb + SZW;
    unsigned short* wqT   = woutb + SZW;        // transposed bf16 first-layer weights
    unsigned short* wkT   = wqT + SZW;
    unsigned short* wvT   = wkT + SZW;
    unsigned short* weq   = wvT + SZW;          // fused W_eff = W_p @ W
    unsigned short* wek   = weq + SZW;
    unsigned short* wev   = wek + SZW;
    unsigned short* qbuf  = wev + SZW;
    unsigned short* kbuf  = qbuf + SZX;
    unsigned short* vtbuf = kbuf + SZX;
    unsigned short* ao    = vtbuf + SZX;
    // total: 5*SZX + 10*SZW shorts ~= 105 MB

    // 1) prep: 3 transposed converts + 4 straight weight converts, one launch
    PrepArgs pa;
    pa.tsrc[0] = W_q;  pa.tsrc[1] = W_k;  pa.tsrc[2] = W_v;
    pa.tdst[0] = wqT;  pa.tdst[1] = wkT;  pa.tdst[2] = wvT;
    pa.csrc[0] = W_qp;  pa.cdst[0] = wqpb;
    pa.csrc[1] = W_kp;  pa.cdst[1] = wkpb;
    pa.csrc[2] = W_vp;  pa.cdst[2] = wvpb;
    pa.csrc[3] = W_out; pa.cdst[3] = woutb;
    prep_all<<<dim3(16, 16, 7), 256, 0, stream>>>(pa);

    // 2) weight fusion W_eff = W_p @ W (z 0..2) CONCURRENT with x bf16 cvt
    FuseXArgs fx;
    fx.g.A[0] = wqpb; fx.g.A[1] = wkpb; fx.g.A[2] = wvpb;
    fx.g.B[0] = wqT;  fx.g.B[1] = wkT;  fx.g.B[2] = wvT;
    fx.g.C[0] = weq;  fx.g.C[1] = wek;  fx.g.C[2] = wev;
    fx.g.mode[0] = 0; fx.g.mode[1] = 0; fx.g.mode[2] = 0;
    fx.g.scl[0] = 1.f; fx.g.scl[1] = 1.f; fx.g.scl[2] = 1.f;
    fx.xsrc = x;
    fx.xdst = xb;
    gemm_fuse_xcvt<<<dim3(8, 8, 6), 256, 0, stream>>>(fx);

    // 3) projections: q = (x@Weq^T)*0.125*log2e, k = x@Wek^T, v^T = (x@Wev^T)^T
    //    (mode 2 writes vtbuf with the 32-key-group permutation for flash PV)
    BGemmArgs pj;
    pj.A[0] = xb;   pj.A[1] = xb;   pj.A[2] = xb;
    pj.B[0] = weq;  pj.B[1] = wek;  pj.B[2] = wev;
    pj.C[0] = qbuf; pj.C[1] = kbuf; pj.C[2] = vtbuf;
    pj.mode[0] = 0; pj.mode[1] = 0; pj.mode[2] = 2;
    pj.scl[0] = 0.18033688f; pj.scl[1] = 1.f; pj.scl[2] = 1.f;
    gemm_bf16nt<<<dim3(8, 64, 3), 256, 0, stream>>>(pj, MROWS, EMBED, EMBED);

    // 4) flash attention
    flash_bf16<<<dim3(LSEQ / 128, NB * NH), 256, 0, stream>>>(qbuf, kbuf, vtbuf, ao);

    // 5) out = ao @ W_out^T (fp32 out)
    BGemmArgs og;
    og.A[0] = ao;    og.A[1] = ao;    og.A[2] = ao;
    og.B[0] = woutb; og.B[1] = woutb; og.B[2] = woutb;
    og.C[0] = d_out; og.C[1] = d_out; og.C[2] = d_out;
    og.mode[0] = 1; og.mode[1] = 1; og.mode[2] = 1;
    og.scl[0] = 1.f; og.scl[1] = 1.f; og.scl[2] = 1.f;
    gemm_bf16nt<<<dim3(8, 64, 1), 256, 0, stream>>>(og, MROWS, EMBED, EMBED);
}

// Round 8
// 279.266 us; speedup vs baseline: 1.0108x; 1.0108x over previous
//
#include <hip/hip_runtime.h>
#include <cstddef>
#include <cstdint>

#define EMBED 1024
#define NH    16
#define DQ    64
#define NB    4
#define LSEQ  2048
#define MROWS (NB * LSEQ)   // 8192

typedef __bf16 bf16x8 __attribute__((ext_vector_type(8)));
typedef float  f32x4  __attribute__((ext_vector_type(4)));

// bf16 round-half-up: bias then take high 16. (RNE differs only on exact ties.)
__device__ __forceinline__ unsigned short f2bf(float f) {
    return (unsigned short)((__float_as_uint(f) + 0x8000u) >> 16);
}

// two floats -> packed bf16x2, round-half-up: 2 bias adds + 1 v_perm_b32.
__device__ __forceinline__ unsigned pack2(float a, float b) {
    unsigned ua = __float_as_uint(a) + 0x8000u;
    unsigned ub = __float_as_uint(b) + 0x8000u;
    return __builtin_amdgcn_perm(ub, ua, 0x07060302u);  // [b.hi16 : a.hi16]
}

__device__ __forceinline__ uint2 pack4(float a, float b, float c, float d) {
    return make_uint2(pack2(a, b), pack2(c, d));
}

// truncating pack (1 v_perm, no bias). Used for P where the bias cancels in
// the O = (P@V)/(P@1) ratio since l is computed from the same truncated P.
__device__ __forceinline__ unsigned pack2t(float a, float b) {
    return __builtin_amdgcn_perm(__float_as_uint(b), __float_as_uint(a), 0x07060302u);
}

// async global -> LDS, 16 B per lane. LDS dest = l + lane*16 (wave-uniform base l).
__device__ __forceinline__ void async_cp16(const void* g, void* l) {
    __builtin_amdgcn_global_load_lds((const __attribute__((address_space(1))) unsigned int*)g,
                                     (__attribute__((address_space(3))) unsigned int*)l,
                                     16, 0, 0);
}

// ---------------- prep: weight converts + transposed converts, ONE launch --
// grid (16,16,7): z 0..2 = transpose_cvt of Wq/Wk/Wv (64x64 tiles),
//                 z 3..6 = straight cvt of Wqp/Wkp/Wvp/Wout (grid-stride).
struct PrepArgs {
    const float* tsrc[3];
    unsigned short* tdst[3];
    const float* csrc[4];
    unsigned short* cdst[4];
};

__global__ __launch_bounds__(256) void prep_all(PrepArgs pa) {
    const int tid = threadIdx.x;
    if (blockIdx.z < 3) {
        __shared__ unsigned short Ts[64][68];
        const float* src = pa.tsrc[blockIdx.z];
        unsigned short* dst = pa.tdst[blockIdx.z];
        const int r0 = blockIdx.y * 64;
        const int c0 = blockIdx.x * 64;
        {
            int col4 = tid & 15;
            int rb   = tid >> 4;
#pragma unroll
            for (int it = 0; it < 4; it++) {
                int r = rb + it * 16;
                float4 f = *(const float4*)(src + (size_t)(r0 + r) * 1024 + c0 + col4 * 4);
                *(uint2*)&Ts[r][col4 * 4] = pack4(f.x, f.y, f.z, f.w);
            }
        }
        __syncthreads();
        {
            int oc = tid >> 2;
            int seg = tid & 3;
            __attribute__((aligned(16))) unsigned short tmp[16];
#pragma unroll
            for (int e = 0; e < 16; e++) tmp[e] = Ts[seg * 16 + e][oc];
            unsigned short* out = dst + (size_t)(c0 + oc) * 1024 + r0 + seg * 16;
            *(uint4*)(out)     = *(const uint4*)&tmp[0];
            *(uint4*)(out + 8) = *(const uint4*)&tmp[8];
        }
    } else {
        int job = blockIdx.z - 3;
        const float* s = pa.csrc[job];
        unsigned short* d = pa.cdst[job];
        const int n4 = (1024 * 1024) >> 2;
        int flat = blockIdx.y * 16 + blockIdx.x;            // 0..255
        for (int i = flat * 256 + tid; i < n4; i += 256 * 256) {
            float4 f = ((const float4*)s)[i];
            ((uint2*)d)[i] = pack4(f.x, f.y, f.z, f.w);
        }
    }
}

// ---------------- bf16 NT GEMM core: C = A(MxK) @ B(NxK)^T ----------------
// 128x128 tile, BK=64 (32 KB LDS, 32 MFMA per barrier pair), 256 threads =
// 4 waves, each wave a 64x64 quadrant of 4x4 mfma_f32_16x16x32_bf16.
// Staging via global_load_lds w=16 with xor chunk swizzle:
//   LDS chunk c (16B) holds global (row r=c>>3, k-chunk (c&7)^(r&7)).
// XCD-chunked block swizzle (per-z nwg is a multiple of 8 in all our
// launches -> bijective): the 8 blocks sharing one A row-panel land on ONE
// XCD's L2 instead of 8, cutting A re-fetch ~8x.
//
// Callers use __launch_bounds__(256, 4): gfx950 has a UNIFIED VGPR/AGPR
// file; default allocation was 88 VGPR + 64 AGPR = 152 -> (128,256] bin ->
// 2 blocks/CU -> MfmaUtil 27%. Forcing 4 waves/EU fits VGPR+AGPR <= 128
// -> 4 blocks/CU (R5: projection 76 -> ~52 us).
//
// mode: 0 = bf16 row-major (acc*scl), 1 = fp32 row-major,
// mode 2 = bf16 C^T (ld=M) with KEY-PERMUTED rows for the flash PV B-layout:
//   within each 32-row group, row 16h+4g+e  is stored at  8g+4h+e.
//   (PV contracts V^T and P^T over the same permuted index; permutation
//   applied identically to both operands leaves the product unchanged.)
//   Transposes through LDS so global writes stay 8B-unit contiguous runs.
struct BGemmArgs {
    const unsigned short* A[3];
    const unsigned short* B[3];
    void* C[3];
    int mode[3];
    float scl[3];
};

__device__ __forceinline__ void gemm_core(const BGemmArgs& p, int M, int N, int K,
                                          unsigned short* SMEM) {
    unsigned short* As = SMEM;
    unsigned short* Bs = SMEM + 128 * 64;

    const int tid  = threadIdx.x;
    const int wave = tid >> 6;
    const int lane = tid & 63;
    const int m16  = lane & 15;
    const int kq   = lane >> 4;

    // XCD swizzle within the z-slice (nwg % 8 == 0 for all our grids).
    const int nwg  = gridDim.x * gridDim.y;
    const int flat = blockIdx.y * gridDim.x + blockIdx.x;
    const int swz  = (flat & 7) * (nwg >> 3) + (flat >> 3);
    const int bm = (swz / gridDim.x) * 128;
    const int bn = (swz % gridDim.x) * 128;
    const int z  = blockIdx.z;
    const unsigned short* A = p.A[z];
    const unsigned short* B = p.B[z];

    f32x4 acc[4][4];
#pragma unroll
    for (int i = 0; i < 4; i++)
#pragma unroll
        for (int j = 0; j < 4; j++) acc[i][j] = f32x4{0.f, 0.f, 0.f, 0.f};

    const int wr = (wave >> 1) * 64;
    const int wc = (wave & 1) * 64;

    for (int k0 = 0; k0 < K; k0 += 64) {
#pragma unroll
        for (int it = 0; it < 4; it++) {
            int c = tid + it * 256;         // chunk 0..1023
            int r = c >> 3;                 // tile row 0..127
            int kc = (c & 7) ^ (r & 7);     // swizzled k-chunk in row
            async_cp16(A + (size_t)(bm + r) * K + k0 + kc * 8,
                       &As[(it * 256 + wave * 64) * 8]);
            async_cp16(B + (size_t)(bn + r) * K + k0 + kc * 8,
                       &Bs[(it * 256 + wave * 64) * 8]);
        }
        __syncthreads();

#pragma unroll
        for (int s = 0; s < 2; s++) {
            bf16x8 af[4], bfr[4];
#pragma unroll
            for (int i = 0; i < 4; i++) {
                int ra = wr + i * 16 + m16;
                af[i] = *reinterpret_cast<const bf16x8*>(
                    &As[ra * 64 + (((s * 4 + kq) ^ (ra & 7)) * 8)]);
                int rb = wc + i * 16 + m16;
                bfr[i] = *reinterpret_cast<const bf16x8*>(
                    &Bs[rb * 64 + (((s * 4 + kq) ^ (rb & 7)) * 8)]);
            }
#pragma unroll
            for (int i = 0; i < 4; i++)
#pragma unroll
                for (int j = 0; j < 4; j++)
                    acc[i][j] = __builtin_amdgcn_mfma_f32_16x16x32_bf16(af[i], bfr[j], acc[i][j], 0, 0, 0);
        }
        __syncthreads();
    }

    const int mode = p.mode[z];
    const float scl = p.scl[z];
    if (mode == 0) {
        unsigned short* Cb = (unsigned short*)p.C[z];
#pragma unroll
        for (int i = 0; i < 4; i++)
#pragma unroll
            for (int j = 0; j < 4; j++) {
                int row = bm + wr + i * 16 + kq * 4;
                int col = bn + wc + j * 16 + m16;
#pragma unroll
                for (int q = 0; q < 4; q++)
                    Cb[(size_t)(row + q) * N + col] = f2bf(acc[i][j][q] * scl);
            }
    } else if (mode == 1) {
        float* Cf = (float*)p.C[z];
#pragma unroll
        for (int i = 0; i < 4; i++)
#pragma unroll
            for (int j = 0; j < 4; j++) {
                int row = bm + wr + i * 16 + kq * 4;
                int col = bn + wc + j * 16 + m16;
#pragma unroll
                for (int q = 0; q < 4; q++)
                    Cf[(size_t)(row + q) * N + col] = acc[i][j][q];
            }
    } else {
        // C^T through LDS. Last loop iteration ended with __syncthreads(),
        // so As/Bs are free to reuse as the 128x128 bf16 transpose buffer.
        // Layout: Tt[col][row-unit], row-unit = 4 rows (8 B). Add-rotate
        // swizzle u' = (u + 2*col) & 31 spreads banks (<=2-way conflicts)
        // with zero padding, so the buffer is exactly 32 KB.
        unsigned short* Tt = SMEM;
#pragma unroll
        for (int i = 0; i < 4; i++)
#pragma unroll
            for (int j = 0; j < 4; j++) {
                int c = wc + j * 16 + m16;          // local col 0..127 (N-dim)
                int u = (wr >> 2) + i * 4 + kq;     // row unit 0..31 (M-dim/4)
                int us = (u + 2 * c) & 31;
                *reinterpret_cast<uint2*>(&Tt[c * 128 + us * 4]) =
                    pack4(acc[i][j][0], acc[i][j][1], acc[i][j][2], acc[i][j][3]);
            }
        __syncthreads();
        unsigned short* Ct = (unsigned short*)p.C[z];
        int r8 = tid & 15;          // 8-row chunk within tile
        int cb = tid >> 4;          // col offset within pass
#pragma unroll
        for (int pass = 0; pass < 8; pass++) {
            int c  = pass * 16 + cb;
            int u0 = r8 * 2;                       // even -> us,us+1 contiguous
            int us = (u0 + 2 * c) & 31;
            uint4 val = *reinterpret_cast<const uint4*>(&Tt[c * 128 + us * 4]);
            // Key-permuted write: rows key0..key0+7 split into two 4-row
            // (8 B) units at permuted positions p = 8g + 4h + e (h = bit4,
            // g = bits3:2 of the local-32 row index). dst1 = dst0 + 8.
            int key0 = r8 * 8;                     // local row base, step 8
            int loc  = key0 & 31;                  // 0, 8, 16, 24
            int dst0 = (key0 & 96) + (((loc & 15) >> 2) * 8) + ((loc >> 4) * 4);
            unsigned short* out = &Ct[(size_t)(bn + c) * M + bm + dst0];
            *reinterpret_cast<uint2*>(out)     = make_uint2(val.x, val.y);
            *reinterpret_cast<uint2*>(out + 8) = make_uint2(val.z, val.w);
        }
    }
}

__global__ __launch_bounds__(256, 4) void gemm_bf16nt(BGemmArgs p, int M, int N, int K) {
    __shared__ __align__(16) unsigned short SMEM[2 * 128 * 64];
    gemm_core(p, M, N, K, SMEM);
}

// ---------------- fusion GEMM + x-convert, ONE launch ----------------
// z 0..2 = weight-fusion GEMM, z 3..5 = x fp32->bf16 cvt on the idle CUs.
struct FuseXArgs {
    BGemmArgs g;
    const float* xsrc;
    unsigned short* xdst;
};

__global__ __launch_bounds__(256, 4) void gemm_fuse_xcvt(FuseXArgs fa) {
    if (blockIdx.z < 3) {
        __shared__ __align__(16) unsigned short SMEM[2 * 128 * 64];
        gemm_core(fa.g, 1024, 1024, 1024, SMEM);
    } else {
        const int n4 = (MROWS * EMBED) >> 2;              // 2,097,152 float4
        int slice = blockIdx.z - 3;
        int flat  = blockIdx.y * gridDim.x + blockIdx.x;  // 0..63
        int start = (slice * 64 + flat) * 256 + threadIdx.x;
        const float4* s = (const float4*)fa.xsrc;
        uint2* d = (uint2*)fa.xdst;
        for (int i = start; i < n4; i += 192 * 256) {
            float4 f = s[i];
            d[i] = pack4(f.x, f.y, f.z, f.w);
        }
    }
}

// ---------------- flash attention, bf16 MFMA, no-max softmax ----------------
// Q is pre-scaled by 0.125*log2(e) in the projection GEMM epilogue, so
//   p = exp2(k.q_scaled) == exp(q.k/8)  (|q.k/8| <~ 2 -> no-max is safe).
// Row-sum l is folded into the PV stage: extra MFMAs with an all-ones
// A-fragment compute column sums of P^T; in the C/D layout every lane then
// holds l for its own q-column in all regs -> no adds, no shuffles.
// P is packed to bf16 by TRUNCATION; bias cancels in O = (P@V)/(P@1).
// Orientation: St = K @ Q^T (m=key, n=qrow), O^T = V^T @ P^T (m=d, n=qrow).
// Block: 128 q-rows, 4 waves, wave owns 32 q-rows. Key-tile 64. Grid 1024.
//
// v8: REMOVED per-cluster s_setprio toggles + hand-interleaved tile body.
//     Diagnosis: MfmaUtil 44 + VALUBusy 43 with wall = SUM of pipe demands;
//     exp2 (quarter-rate, ~1024 cyc/SIMD/tile) was not hiding under MFMA.
//     The setprio intrinsics are side-effecting scheduler fences that pinned
//     the QK-MFMA / exp2+pack-VALU / PV-MFMA phases into disjoint regions
//     (m190: setprio is null-to-negative on barrier-synced lockstep
//     structures like this one). New order gives the scheduler adjacent
//     independent MFMA work for every VALU burst:
//       QK(0) QK(1) exp2(0,1) QK(2) pack(t0) QK(3) PV(t0) exp2(2,3)
//       pack(t1) PV(t1)
//     phase_skew (R7) REVERTED: no counter change -> lockstep theory dead.
//     Keeps v5-v6: key-permuted zero-shuffle PV at K=32, Pt LDS deleted,
//     K/V dbuf 32 KB, stage(next) at iter top + single vmcnt(0)+s_barrier
//     at iter end, XCD swizzle, shared zero4 C-in.
__global__ __launch_bounds__(256, 4)
void flash_bf16(const unsigned short* __restrict__ qb,
                const unsigned short* __restrict__ kb,
                const unsigned short* __restrict__ vtb,
                unsigned short* __restrict__ ao) {
    __shared__ __align__(16) unsigned short Ks[2][64 * 64];
    __shared__ __align__(16) unsigned short Vt[2][64 * 64];

    const int tid  = threadIdx.x;
    const int wave = tid >> 6;
    const int lane = tid & 63;
    const int m16  = lane & 15;
    const int kq   = lane >> 4;

    // XCD swizzle: linear dispatch id -> 128-contiguous chunk per XCD.
    const int flat = blockIdx.y * (LSEQ / 128) + blockIdx.x;   // 0..1023
    const int swz  = (flat & 7) * 128 + (flat >> 3);
    const int bh   = swz >> 4;               // 0..63
    const int nn   = bh >> 4;                // batch
    const int h    = bh & 15;                // head
    const int q0   = (swz & 15) * 128;       // query tile base

    // all-ones A-fragment (bf16 1.0 = 0x3F80) for the l-row MFMAs
    const uint4 ones_u = make_uint4(0x3F803F80u, 0x3F803F80u, 0x3F803F80u, 0x3F803F80u);
    const bf16x8 ones8 = __builtin_bit_cast(bf16x8, ones_u);

    const unsigned short* kptr  = kb + (size_t)(nn * LSEQ) * EMBED + h * DQ;
    const unsigned short* vtptr = vtb + (size_t)(h * DQ) * MROWS + nn * LSEQ;

    auto stage = [&](int buf) {
#pragma unroll
        for (int it = 0; it < 2; it++) {
            int c = tid + it * 256;            // chunk 0..511
            int r = c >> 3;                    // row 0..63
            int kc = (c & 7) ^ (r & 7);        // swizzled chunk in row
            async_cp16(kptr + (size_t)r * EMBED + kc * 8,
                       &Ks[buf][(it * 256 + wave * 64) * 8]);
            async_cp16(vtptr + (size_t)r * MROWS + kc * 8,
                       &Vt[buf][(it * 256 + wave * 64) * 8]);
        }
        kptr  += 64 * EMBED;
        vtptr += 64;
    };

    // prologue: stage tile 0; Q fragment loads overlap the staging.
    stage(0);

    // Q fragments: qf[j][s] = Q[q0+wave*32+j*16+m16][s*32 + kq*8 .. +7]
    bf16x8 qf[2][2];
#pragma unroll
    for (int j = 0; j < 2; j++) {
        size_t tok = (size_t)(nn * LSEQ + q0 + wave * 32 + j * 16 + m16);
#pragma unroll
        for (int s = 0; s < 2; s++)
            qf[j][s] = *reinterpret_cast<const bf16x8*>(
                &qb[tok * EMBED + h * DQ + s * 32 + kq * 8]);
    }

    f32x4 o[4][2];   // o[mt][j]: O^T tile (d = mt*16+kq*4+reg, qcol = j*16+m16)
    f32x4 o4[2];     // l accumulator (all regs equal per lane)
#pragma unroll
    for (int j = 0; j < 2; j++) {
        o4[j] = f32x4{0.f, 0.f, 0.f, 0.f};
#pragma unroll
        for (int mt = 0; mt < 4; mt++) o[mt][j] = f32x4{0.f, 0.f, 0.f, 0.f};
    }
    const f32x4 zero4 = f32x4{0.f, 0.f, 0.f, 0.f};   // shared MFMA C-in

    asm volatile("s_waitcnt vmcnt(0)" ::: "memory");   // tile 0 + Q landed
    __builtin_amdgcn_s_barrier();
    asm volatile("" ::: "memory");

    const int NT = LSEQ / 64;    // 32

    // per-tile building blocks (interleaved in the loop body below)
    f32x4 st[4][2];
    bf16x8 pb[2];

#define QK_STEP(i)                                                             \
    {                                                                          \
        int key_ = (i) * 16 + m16;                                             \
        bf16x8 a0_ = *reinterpret_cast<const bf16x8*>(                         \
            &Ks[cur][key_ * 64 + (((kq) ^ (m16 & 7)) * 8)]);                   \
        bf16x8 a1_ = *reinterpret_cast<const bf16x8*>(                         \
            &Ks[cur][key_ * 64 + (((4 + kq) ^ (m16 & 7)) * 8)]);               \
        st[i][0] = __builtin_amdgcn_mfma_f32_16x16x32_bf16(a0_, qf[0][0], zero4, 0, 0, 0); \
        st[i][1] = __builtin_amdgcn_mfma_f32_16x16x32_bf16(a0_, qf[1][0], zero4, 0, 0, 0); \
        st[i][0] = __builtin_amdgcn_mfma_f32_16x16x32_bf16(a1_, qf[0][1], st[i][0], 0, 0, 0); \
        st[i][1] = __builtin_amdgcn_mfma_f32_16x16x32_bf16(a1_, qf[1][1], st[i][1], 0, 0, 0); \
    }

#define EXP2_STEP(i)                                                           \
    {                                                                          \
        _Pragma("unroll")                                                      \
        for (int j_ = 0; j_ < 2; j_++)                                         \
            _Pragma("unroll")                                                  \
            for (int q_ = 0; q_ < 4; q_++)                                     \
                st[i][j_][q_] = __builtin_amdgcn_exp2f(st[i][j_][q_]);         \
    }

#define PACK_STEP(t)                                                           \
    {                                                                          \
        _Pragma("unroll")                                                      \
        for (int j_ = 0; j_ < 2; j_++) {                                       \
            uint4 pu_;                                                         \
            pu_.x = pack2t(st[2*(t)][j_][0],   st[2*(t)][j_][1]);              \
            pu_.y = pack2t(st[2*(t)][j_][2],   st[2*(t)][j_][3]);              \
            pu_.z = pack2t(st[2*(t)+1][j_][0], st[2*(t)+1][j_][1]);            \
            pu_.w = pack2t(st[2*(t)+1][j_][2], st[2*(t)+1][j_][3]);            \
            pb[j_] = __builtin_bit_cast(bf16x8, pu_);                          \
        }                                                                      \
    }

#define PV_STEP(t)                                                             \
    {                                                                          \
        bf16x8 av8_[4];                                                        \
        _Pragma("unroll")                                                      \
        for (int mt_ = 0; mt_ < 4; mt_++) {                                    \
            int d_ = mt_ * 16 + m16;                                           \
            av8_[mt_] = *reinterpret_cast<const bf16x8*>(                      \
                &Vt[cur][d_ * 64 + ((((t) * 4 + kq) ^ (m16 & 7)) * 8)]);       \
        }                                                                      \
        _Pragma("unroll")                                                      \
        for (int mt_ = 0; mt_ < 4; mt_++)                                      \
            _Pragma("unroll")                                                  \
            for (int j_ = 0; j_ < 2; j_++)                                     \
                o[mt_][j_] = __builtin_amdgcn_mfma_f32_16x16x32_bf16(av8_[mt_], pb[j_], o[mt_][j_], 0, 0, 0); \
        _Pragma("unroll")                                                      \
        for (int j_ = 0; j_ < 2; j_++)                                         \
            o4[j_] = __builtin_amdgcn_mfma_f32_16x16x32_bf16(ones8, pb[j_], o4[j_], 0, 0, 0); \
    }

    for (int kt = 0; kt < NT; kt++) {
        const int cur = kt & 1;
        if (kt + 1 < NT) stage(cur ^ 1);   // prefetch next tile (no wait)

        // Interleaved body: every VALU burst (exp2/pack) has independent
        // MFMA work adjacent in program order.
        QK_STEP(0)
        QK_STEP(1)
        EXP2_STEP(0)
        EXP2_STEP(1)
        QK_STEP(2)
        PACK_STEP(0)
        QK_STEP(3)
        PV_STEP(0)
        EXP2_STEP(2)
        EXP2_STEP(3)
        PACK_STEP(1)
        PV_STEP(1)

        // Release buf[cur] for next iter's stage; next tile's loads (issued
        // at iter top) drained here, hidden under the compute above.
        if (kt + 1 < NT) {
            asm volatile("s_waitcnt vmcnt(0)" ::: "memory");
            __builtin_amdgcn_s_barrier();
            asm volatile("" ::: "memory");
        }
    }

#undef QK_STEP
#undef EXP2_STEP
#undef PACK_STEP
#undef PV_STEP

    // Epilogue: normalize by l (= o4[j][0], identical in all regs), write ao.
#pragma unroll
    for (int j = 0; j < 2; j++) {
        float inv = 1.f / o4[j][0];
        size_t tok = (size_t)(nn * LSEQ + q0 + wave * 32 + j * 16 + m16);
#pragma unroll
        for (int mt = 0; mt < 4; mt++) {
            *reinterpret_cast<uint2*>(&ao[tok * EMBED + h * DQ + mt * 16 + kq * 4]) =
                pack4(o[mt][j][0] * inv, o[mt][j][1] * inv, o[mt][j][2] * inv, o[mt][j][3] * inv);
        }
    }
}

// ---------------- host ----------------
extern "C" void kernel_launch(void* const* d_in, const int* in_sizes, int n_in,
                              void* d_out, int out_size, void* d_ws, size_t ws_size,
                              hipStream_t stream) {
    (void)in_sizes; (void)n_in; (void)out_size; (void)ws_size;
    const float* x     = (const float*)d_in[0];
    const float* W_q   = (const float*)d_in[1];
    const float* W_k   = (const float*)d_in[2];
    const float* W_v   = (const float*)d_in[3];
    const float* W_qp  = (const float*)d_in[4];
    const float* W_kp  = (const float*)d_in[5];
    const float* W_vp  = (const float*)d_in[6];
    const float* W_out = (const float*)d_in[7];

    unsigned short* ws16 = (unsigned short*)d_ws;
    const size_t SZX = (size_t)MROWS * EMBED;   // 8,388,608
    const size_t SZW = (size_t)EMBED * EMBED;   // 1,048,576

    unsigned short* xb    = ws16;
    unsigned short* wqpb  = xb + SZX;
    unsigned short* wkpb  = wqpb + SZW;
    unsigned short* wvpb  = wkpb + SZW;
    unsigned short* woutb = wvpb + SZW;
    unsigned short* wqT   = woutb + SZW;        // transposed bf16 first-layer weights
    unsigned short* wkT   = wqT + SZW;
    unsigned short* wvT   = wkT + SZW;
    unsigned short* weq   = wvT + SZW;          // fused W_eff = W_p @ W
    unsigned short* wek   = weq + SZW;
    unsigned short* wev   = wek + SZW;
    unsigned short* qbuf  = wev + SZW;
    unsigned short* kbuf  = qbuf + SZX;
    unsigned short* vtbuf = kbuf + SZX;
    unsigned short* ao    = vtbuf + SZX;
    // total: 5*SZX + 10*SZW shorts ~= 105 MB

    // 1) prep: 3 transposed converts + 4 straight weight converts, one launch
    PrepArgs pa;
    pa.tsrc[0] = W_q;  pa.tsrc[1] = W_k;  pa.tsrc[2] = W_v;
    pa.tdst[0] = wqT;  pa.tdst[1] = wkT;  pa.tdst[2] = wvT;
    pa.csrc[0] = W_qp;  pa.cdst[0] = wqpb;
    pa.csrc[1] = W_kp;  pa.cdst[1] = wkpb;
    pa.csrc[2] = W_vp;  pa.cdst[2] = wvpb;
    pa.csrc[3] = W_out; pa.cdst[3] = woutb;
    prep_all<<<dim3(16, 16, 7), 256, 0, stream>>>(pa);

    // 2) weight fusion W_eff = W_p @ W (z 0..2) CONCURRENT with x bf16 cvt
    FuseXArgs fx;
    fx.g.A[0] = wqpb; fx.g.A[1] = wkpb; fx.g.A[2] = wvpb;
    fx.g.B[0] = wqT;  fx.g.B[1] = wkT;  fx.g.B[2] = wvT;
    fx.g.C[0] = weq;  fx.g.C[1] = wek;  fx.g.C[2] = wev;
    fx.g.mode[0] = 0; fx.g.mode[1] = 0; fx.g.mode[2] = 0;
    fx.g.scl[0] = 1.f; fx.g.scl[1] = 1.f; fx.g.scl[2] = 1.f;
    fx.xsrc = x;
    fx.xdst = xb;
    gemm_fuse_xcvt<<<dim3(8, 8, 6), 256, 0, stream>>>(fx);

    // 3) projections: q = (x@Weq^T)*0.125*log2e, k = x@Wek^T, v^T = (x@Wev^T)^T
    //    (mode 2 writes vtbuf with the 32-key-group permutation for flash PV)
    BGemmArgs pj;
    pj.A[0] = xb;   pj.A[1] = xb;   pj.A[2] = xb;
    pj.B[0] = weq;  pj.B[1] = wek;  pj.B[2] = wev;
    pj.C[0] = qbuf; pj.C[1] = kbuf; pj.C[2] = vtbuf;
    pj.mode[0] = 0; pj.mode[1] = 0; pj.mode[2] = 2;
    pj.scl[0] = 0.18033688f; pj.scl[1] = 1.f; pj.scl[2] = 1.f;
    gemm_bf16nt<<<dim3(8, 64, 3), 256, 0, stream>>>(pj, MROWS, EMBED, EMBED);

    // 4) flash attention
    flash_bf16<<<dim3(LSEQ / 128, NB * NH), 256, 0, stream>>>(qbuf, kbuf, vtbuf, ao);

    // 5) out = ao @ W_out^T (fp32 out)
    BGemmArgs og;
    og.A[0] = ao;    og.A[1] = ao;    og.A[2] = ao;
    og.B[0] = woutb; og.B[1] = woutb; og.B[2] = woutb;
    og.C[0] = d_out; og.C[1] = d_out; og.C[2] = d_out;
    og.mode[0] = 1; og.mode[1] = 1; og.mode[2] = 1;
    og.scl[0] = 1.f; og.scl[1] = 1.f; og.scl[2] = 1.f;
    gemm_bf16nt<<<dim3(8, 64, 1), 256, 0, stream>>>(og, MROWS, EMBED, EMBED);
}

// Round 9
// 264.785 us; speedup vs baseline: 1.0661x; 1.0547x over previous
//
#include <hip/hip_runtime.h>
#include <cstddef>
#include <cstdint>

#define EMBED 1024
#define NH    16
#define DQ    64
#define NB    4
#define LSEQ  2048
#define MROWS (NB * LSEQ)   // 8192

typedef __bf16 bf16x8 __attribute__((ext_vector_type(8)));
typedef float  f32x4  __attribute__((ext_vector_type(4)));

// bf16 round-half-up: bias then take high 16. (RNE differs only on exact ties.)
__device__ __forceinline__ unsigned short f2bf(float f) {
    return (unsigned short)((__float_as_uint(f) + 0x8000u) >> 16);
}

// two floats -> packed bf16x2, round-half-up: 2 bias adds + 1 v_perm_b32.
__device__ __forceinline__ unsigned pack2(float a, float b) {
    unsigned ua = __float_as_uint(a) + 0x8000u;
    unsigned ub = __float_as_uint(b) + 0x8000u;
    return __builtin_amdgcn_perm(ub, ua, 0x07060302u);  // [b.hi16 : a.hi16]
}

__device__ __forceinline__ uint2 pack4(float a, float b, float c, float d) {
    return make_uint2(pack2(a, b), pack2(c, d));
}

// truncating pack (1 v_perm, no bias). Used for P where the bias cancels in
// the O = (P@V)/(P@1) ratio since l is computed from the same truncated P.
__device__ __forceinline__ unsigned pack2t(float a, float b) {
    return __builtin_amdgcn_perm(__float_as_uint(b), __float_as_uint(a), 0x07060302u);
}

// async global -> LDS, 16 B per lane. LDS dest = l + lane*16 (wave-uniform base l).
__device__ __forceinline__ void async_cp16(const void* g, void* l) {
    __builtin_amdgcn_global_load_lds((const __attribute__((address_space(1))) unsigned int*)g,
                                     (__attribute__((address_space(3))) unsigned int*)l,
                                     16, 0, 0);
}

// ---------------- prep: weight converts + transposed converts, ONE launch --
// grid (16,16,7): z 0..2 = transpose_cvt of Wq/Wk/Wv (64x64 tiles),
//                 z 3..6 = straight cvt of Wqp/Wkp/Wvp/Wout (grid-stride).
struct PrepArgs {
    const float* tsrc[3];
    unsigned short* tdst[3];
    const float* csrc[4];
    unsigned short* cdst[4];
};

__global__ __launch_bounds__(256) void prep_all(PrepArgs pa) {
    const int tid = threadIdx.x;
    if (blockIdx.z < 3) {
        __shared__ unsigned short Ts[64][68];
        const float* src = pa.tsrc[blockIdx.z];
        unsigned short* dst = pa.tdst[blockIdx.z];
        const int r0 = blockIdx.y * 64;
        const int c0 = blockIdx.x * 64;
        {
            int col4 = tid & 15;
            int rb   = tid >> 4;
#pragma unroll
            for (int it = 0; it < 4; it++) {
                int r = rb + it * 16;
                float4 f = *(const float4*)(src + (size_t)(r0 + r) * 1024 + c0 + col4 * 4);
                *(uint2*)&Ts[r][col4 * 4] = pack4(f.x, f.y, f.z, f.w);
            }
        }
        __syncthreads();
        {
            int oc = tid >> 2;
            int seg = tid & 3;
            __attribute__((aligned(16))) unsigned short tmp[16];
#pragma unroll
            for (int e = 0; e < 16; e++) tmp[e] = Ts[seg * 16 + e][oc];
            unsigned short* out = dst + (size_t)(c0 + oc) * 1024 + r0 + seg * 16;
            *(uint4*)(out)     = *(const uint4*)&tmp[0];
            *(uint4*)(out + 8) = *(const uint4*)&tmp[8];
        }
    } else {
        int job = blockIdx.z - 3;
        const float* s = pa.csrc[job];
        unsigned short* d = pa.cdst[job];
        const int n4 = (1024 * 1024) >> 2;
        int flat = blockIdx.y * 16 + blockIdx.x;            // 0..255
        for (int i = flat * 256 + tid; i < n4; i += 256 * 256) {
            float4 f = ((const float4*)s)[i];
            ((uint2*)d)[i] = pack4(f.x, f.y, f.z, f.w);
        }
    }
}

// ---------------- bf16 NT GEMM cores: C = A(MxK) @ B(NxK)^T ----------------
// Shared structure: BK=64, 256 threads = 4 waves, global_load_lds w=16 with
// xor chunk swizzle (LDS chunk c holds global row r=c>>3, k-chunk (c&7)^(r&7)),
// XCD-chunked block swizzle (nwg % 8 == 0 in all launches -> bijective).
// All callers __launch_bounds__(256, 4): gfx950 unified VGPR/AGPR file --
// keeping VGPR+AGPR <= 128 gives 4 blocks/CU (R5: proj 76 -> ~52 us).
//
// gemm_core: 128x128 tile (32 KB LDS, acc 4x4 = 64 AGPR).
//   mode 0 = bf16 row-major (acc*scl), 1 = fp32 row-major,
//   mode 2 = bf16 C^T (ld=M) with KEY-PERMUTED rows for the flash PV
//   B-layout (within each 32-row group, row 16h+4g+e stored at 8g+4h+e;
//   PV contracts both operands over the same permuted index), transposed
//   through LDS so global writes stay 8B-unit contiguous runs.
//
// gemm_n64_core: 128x64 tile (24 KB LDS, acc 4x2 = 32 AGPR). Same math,
//   half-width N. Purpose: occupancy. The output GEMM (512 blocks of
//   128x128 = 2 blocks/CU, grid-limited) and fusion GEMM (192 blocks,
//   <1/CU) were stuck in the 2-blocks/CU regime (R4: MfmaUtil 27%);
//   the n64 tile doubles their grids -> 4 blocks/CU.
struct BGemmArgs {
    const unsigned short* A[3];
    const unsigned short* B[3];
    void* C[3];
    int mode[3];
    float scl[3];
};

__device__ __forceinline__ void gemm_core(const BGemmArgs& p, int M, int N, int K,
                                          unsigned short* SMEM) {
    unsigned short* As = SMEM;
    unsigned short* Bs = SMEM + 128 * 64;

    const int tid  = threadIdx.x;
    const int wave = tid >> 6;
    const int lane = tid & 63;
    const int m16  = lane & 15;
    const int kq   = lane >> 4;

    const int nwg  = gridDim.x * gridDim.y;
    const int flat = blockIdx.y * gridDim.x + blockIdx.x;
    const int swz  = (flat & 7) * (nwg >> 3) + (flat >> 3);
    const int bm = (swz / gridDim.x) * 128;
    const int bn = (swz % gridDim.x) * 128;
    const int z  = blockIdx.z;
    const unsigned short* A = p.A[z];
    const unsigned short* B = p.B[z];

    f32x4 acc[4][4];
#pragma unroll
    for (int i = 0; i < 4; i++)
#pragma unroll
        for (int j = 0; j < 4; j++) acc[i][j] = f32x4{0.f, 0.f, 0.f, 0.f};

    const int wr = (wave >> 1) * 64;
    const int wc = (wave & 1) * 64;

    for (int k0 = 0; k0 < K; k0 += 64) {
#pragma unroll
        for (int it = 0; it < 4; it++) {
            int c = tid + it * 256;         // chunk 0..1023
            int r = c >> 3;                 // tile row 0..127
            int kc = (c & 7) ^ (r & 7);     // swizzled k-chunk in row
            async_cp16(A + (size_t)(bm + r) * K + k0 + kc * 8,
                       &As[(it * 256 + wave * 64) * 8]);
            async_cp16(B + (size_t)(bn + r) * K + k0 + kc * 8,
                       &Bs[(it * 256 + wave * 64) * 8]);
        }
        __syncthreads();

#pragma unroll
        for (int s = 0; s < 2; s++) {
            bf16x8 af[4], bfr[4];
#pragma unroll
            for (int i = 0; i < 4; i++) {
                int ra = wr + i * 16 + m16;
                af[i] = *reinterpret_cast<const bf16x8*>(
                    &As[ra * 64 + (((s * 4 + kq) ^ (ra & 7)) * 8)]);
                int rb = wc + i * 16 + m16;
                bfr[i] = *reinterpret_cast<const bf16x8*>(
                    &Bs[rb * 64 + (((s * 4 + kq) ^ (rb & 7)) * 8)]);
            }
#pragma unroll
            for (int i = 0; i < 4; i++)
#pragma unroll
                for (int j = 0; j < 4; j++)
                    acc[i][j] = __builtin_amdgcn_mfma_f32_16x16x32_bf16(af[i], bfr[j], acc[i][j], 0, 0, 0);
        }
        __syncthreads();
    }

    const int mode = p.mode[z];
    const float scl = p.scl[z];
    if (mode == 0) {
        unsigned short* Cb = (unsigned short*)p.C[z];
#pragma unroll
        for (int i = 0; i < 4; i++)
#pragma unroll
            for (int j = 0; j < 4; j++) {
                int row = bm + wr + i * 16 + kq * 4;
                int col = bn + wc + j * 16 + m16;
#pragma unroll
                for (int q = 0; q < 4; q++)
                    Cb[(size_t)(row + q) * N + col] = f2bf(acc[i][j][q] * scl);
            }
    } else if (mode == 1) {
        float* Cf = (float*)p.C[z];
#pragma unroll
        for (int i = 0; i < 4; i++)
#pragma unroll
            for (int j = 0; j < 4; j++) {
                int row = bm + wr + i * 16 + kq * 4;
                int col = bn + wc + j * 16 + m16;
#pragma unroll
                for (int q = 0; q < 4; q++)
                    Cf[(size_t)(row + q) * N + col] = acc[i][j][q];
            }
    } else {
        // C^T through LDS (buffer reusable: loop ended on __syncthreads()).
        // Tt[col][row-unit(4 rows, 8B)], add-rotate swizzle u'=(u+2c)&31.
        unsigned short* Tt = SMEM;
#pragma unroll
        for (int i = 0; i < 4; i++)
#pragma unroll
            for (int j = 0; j < 4; j++) {
                int c = wc + j * 16 + m16;          // local col 0..127 (N-dim)
                int u = (wr >> 2) + i * 4 + kq;     // row unit 0..31 (M-dim/4)
                int us = (u + 2 * c) & 31;
                *reinterpret_cast<uint2*>(&Tt[c * 128 + us * 4]) =
                    pack4(acc[i][j][0], acc[i][j][1], acc[i][j][2], acc[i][j][3]);
            }
        __syncthreads();
        unsigned short* Ct = (unsigned short*)p.C[z];
        int r8 = tid & 15;          // 8-row chunk within tile
        int cb = tid >> 4;          // col offset within pass
#pragma unroll
        for (int pass = 0; pass < 8; pass++) {
            int c  = pass * 16 + cb;
            int u0 = r8 * 2;                       // even -> us,us+1 contiguous
            int us = (u0 + 2 * c) & 31;
            uint4 val = *reinterpret_cast<const uint4*>(&Tt[c * 128 + us * 4]);
            // Key-permuted write: rows key0..key0+7 split into two 4-row
            // (8 B) units at permuted positions p = 8g + 4h + e.
            int key0 = r8 * 8;                     // local row base, step 8
            int loc  = key0 & 31;                  // 0, 8, 16, 24
            int dst0 = (key0 & 96) + (((loc & 15) >> 2) * 8) + ((loc >> 4) * 4);
            unsigned short* out = &Ct[(size_t)(bn + c) * M + bm + dst0];
            *reinterpret_cast<uint2*>(out)     = make_uint2(val.x, val.y);
            *reinterpret_cast<uint2*>(out + 8) = make_uint2(val.z, val.w);
        }
    }
}

__device__ __forceinline__ void gemm_n64_core(const BGemmArgs& p, int M, int N, int K,
                                              unsigned short* SMEM) {
    unsigned short* As = SMEM;             // 128 x 64
    unsigned short* Bs = SMEM + 128 * 64;  // 64 x 64

    const int tid  = threadIdx.x;
    const int wave = tid >> 6;
    const int lane = tid & 63;
    const int m16  = lane & 15;
    const int kq   = lane >> 4;

    const int nwg  = gridDim.x * gridDim.y;
    const int flat = blockIdx.y * gridDim.x + blockIdx.x;
    const int swz  = (flat & 7) * (nwg >> 3) + (flat >> 3);
    const int bm = (swz / gridDim.x) * 128;
    const int bn = (swz % gridDim.x) * 64;
    const int z  = blockIdx.z;
    const unsigned short* A = p.A[z];
    const unsigned short* B = p.B[z];

    f32x4 acc[4][2];
#pragma unroll
    for (int i = 0; i < 4; i++)
#pragma unroll
        for (int j = 0; j < 2; j++) acc[i][j] = f32x4{0.f, 0.f, 0.f, 0.f};

    const int wr = (wave >> 1) * 64;   // M half
    const int wc = (wave & 1) * 32;    // N half

    for (int k0 = 0; k0 < K; k0 += 64) {
#pragma unroll
        for (int it = 0; it < 4; it++) {
            int c = tid + it * 256;         // chunk 0..1023
            int r = c >> 3;                 // A tile row 0..127
            int kc = (c & 7) ^ (r & 7);
            async_cp16(A + (size_t)(bm + r) * K + k0 + kc * 8,
                       &As[(it * 256 + wave * 64) * 8]);
        }
#pragma unroll
        for (int it = 0; it < 2; it++) {
            int c = tid + it * 256;         // chunk 0..511
            int r = c >> 3;                 // B tile row 0..63
            int kc = (c & 7) ^ (r & 7);
            async_cp16(B + (size_t)(bn + r) * K + k0 + kc * 8,
                       &Bs[(it * 256 + wave * 64) * 8]);
        }
        __syncthreads();

#pragma unroll
        for (int s = 0; s < 2; s++) {
            bf16x8 af[4], bfr[2];
#pragma unroll
            for (int i = 0; i < 4; i++) {
                int ra = wr + i * 16 + m16;
                af[i] = *reinterpret_cast<const bf16x8*>(
                    &As[ra * 64 + (((s * 4 + kq) ^ (ra & 7)) * 8)]);
            }
#pragma unroll
            for (int j = 0; j < 2; j++) {
                int rb = wc + j * 16 + m16;
                bfr[j] = *reinterpret_cast<const bf16x8*>(
                    &Bs[rb * 64 + (((s * 4 + kq) ^ (rb & 7)) * 8)]);
            }
#pragma unroll
            for (int i = 0; i < 4; i++)
#pragma unroll
                for (int j = 0; j < 2; j++)
                    acc[i][j] = __builtin_amdgcn_mfma_f32_16x16x32_bf16(af[i], bfr[j], acc[i][j], 0, 0, 0);
        }
        __syncthreads();
    }

    const int mode = p.mode[z];
    const float scl = p.scl[z];
    if (mode == 0) {
        unsigned short* Cb = (unsigned short*)p.C[z];
#pragma unroll
        for (int i = 0; i < 4; i++)
#pragma unroll
            for (int j = 0; j < 2; j++) {
                int row = bm + wr + i * 16 + kq * 4;
                int col = bn + wc + j * 16 + m16;
#pragma unroll
                for (int q = 0; q < 4; q++)
                    Cb[(size_t)(row + q) * N + col] = f2bf(acc[i][j][q] * scl);
            }
    } else {
        float* Cf = (float*)p.C[z];
#pragma unroll
        for (int i = 0; i < 4; i++)
#pragma unroll
            for (int j = 0; j < 2; j++) {
                int row = bm + wr + i * 16 + kq * 4;
                int col = bn + wc + j * 16 + m16;
#pragma unroll
                for (int q = 0; q < 4; q++)
                    Cf[(size_t)(row + q) * N + col] = acc[i][j][q];
            }
    }
}

__global__ __launch_bounds__(256, 4) void gemm_bf16nt(BGemmArgs p, int M, int N, int K) {
    __shared__ __align__(16) unsigned short SMEM[2 * 128 * 64];
    gemm_core(p, M, N, K, SMEM);
}

__global__ __launch_bounds__(256, 4) void gemm_n64(BGemmArgs p, int M, int N, int K) {
    __shared__ __align__(16) unsigned short SMEM[(128 + 64) * 64];
    gemm_n64_core(p, M, N, K, SMEM);
}

// ---------------- fusion GEMM (n64 tiles) + x-convert, ONE launch ----------
// z 0..2 = weight-fusion GEMM (grid 16x8 = 128 blocks/z -> 384 GEMM blocks,
// up from 192 with 128x128 tiles), z 3..5 = x fp32->bf16 cvt slices.
struct FuseXArgs {
    BGemmArgs g;
    const float* xsrc;
    unsigned short* xdst;
};

__global__ __launch_bounds__(256, 4) void gemm_fuse_xcvt(FuseXArgs fa) {
    if (blockIdx.z < 3) {
        __shared__ __align__(16) unsigned short SMEM[(128 + 64) * 64];
        gemm_n64_core(fa.g, 1024, 1024, 1024, SMEM);
    } else {
        const int n4 = (MROWS * EMBED) >> 2;              // 2,097,152 float4
        int slice = blockIdx.z - 3;
        int flat  = blockIdx.y * gridDim.x + blockIdx.x;  // 0..127
        int start = (slice * 128 + flat) * 256 + threadIdx.x;
        const float4* s = (const float4*)fa.xsrc;
        uint2* d = (uint2*)fa.xdst;
        for (int i = start; i < n4; i += 384 * 256) {
            float4 f = s[i];
            d[i] = pack4(f.x, f.y, f.z, f.w);
        }
    }
}

// ---------------- flash attention, bf16 MFMA, no-max softmax ----------------
// Q is pre-scaled by 0.125*log2(e) in the projection GEMM epilogue, so
//   p = exp2(k.q_scaled) == exp(q.k/8)  (|q.k/8| <~ 2 -> no-max is safe).
// Row-sum l is folded into the PV stage: extra MFMAs with an all-ones
// A-fragment compute column sums of P^T; in the C/D layout every lane then
// holds l for its own q-column in all regs -> no adds, no shuffles.
// P is packed to bf16 by TRUNCATION; bias cancels in O = (P@V)/(P@1).
// Orientation: St = K @ Q^T (m=key, n=qrow), O^T = V^T @ P^T (m=d, n=qrow).
// Block: 128 q-rows, 4 waves, wave owns 32 q-rows. Key-tile 64. Grid 1024.
//
// v9 = exact R5 (v5) body, the best measured config (flash 71.9-72.2 us).
//     R6 VALU-trim: neutral. R7 phase-skew: -3 us. R8 interleave: -2 us.
//     Three scheduling nulls at identical MfmaUtil ~44 / VALUBusy ~43 =>
//     this is the structural floor of the 4-wave/64-key-tile shape.
//     Keeps: key-permuted zero-shuffle PV at K=32 (vtbuf pre-permuted
//     16h+4g+e -> 8g+4h+e per 32-group in the projection epilogue), Pt LDS
//     deleted (bank conflicts 0), K/V dbuf 32 KB, stage(next) at iter top +
//     single vmcnt(0)+s_barrier at iter end, T5 setprio, XCD swizzle.
__global__ __launch_bounds__(256, 4)
void flash_bf16(const unsigned short* __restrict__ qb,
                const unsigned short* __restrict__ kb,
                const unsigned short* __restrict__ vtb,
                unsigned short* __restrict__ ao) {
    __shared__ __align__(16) unsigned short Ks[2][64 * 64];
    __shared__ __align__(16) unsigned short Vt[2][64 * 64];

    const int tid  = threadIdx.x;
    const int wave = tid >> 6;
    const int lane = tid & 63;
    const int m16  = lane & 15;
    const int kq   = lane >> 4;

    // XCD swizzle: linear dispatch id -> 128-contiguous chunk per XCD.
    const int flat = blockIdx.y * (LSEQ / 128) + blockIdx.x;   // 0..1023
    const int swz  = (flat & 7) * 128 + (flat >> 3);
    const int bh   = swz >> 4;               // 0..63
    const int nn   = bh >> 4;                // batch
    const int h    = bh & 15;                // head
    const int q0   = (swz & 15) * 128;       // query tile base

    // all-ones A-fragment (bf16 1.0 = 0x3F80) for the l-row MFMAs
    const uint4 ones_u = make_uint4(0x3F803F80u, 0x3F803F80u, 0x3F803F80u, 0x3F803F80u);
    const bf16x8 ones8 = __builtin_bit_cast(bf16x8, ones_u);

    const unsigned short* kptr  = kb + (size_t)(nn * LSEQ) * EMBED + h * DQ;
    const unsigned short* vtptr = vtb + (size_t)(h * DQ) * MROWS + nn * LSEQ;

    auto stage = [&](int buf) {
#pragma unroll
        for (int it = 0; it < 2; it++) {
            int c = tid + it * 256;            // chunk 0..511
            int r = c >> 3;                    // row 0..63
            int kc = (c & 7) ^ (r & 7);        // swizzled chunk in row
            async_cp16(kptr + (size_t)r * EMBED + kc * 8,
                       &Ks[buf][(it * 256 + wave * 64) * 8]);
            async_cp16(vtptr + (size_t)r * MROWS + kc * 8,
                       &Vt[buf][(it * 256 + wave * 64) * 8]);
        }
        kptr  += 64 * EMBED;
        vtptr += 64;
    };

    // prologue: stage tile 0; Q fragment loads overlap the staging.
    stage(0);

    // Q fragments: qf[j][s] = Q[q0+wave*32+j*16+m16][s*32 + kq*8 .. +7]
    bf16x8 qf[2][2];
#pragma unroll
    for (int j = 0; j < 2; j++) {
        size_t tok = (size_t)(nn * LSEQ + q0 + wave * 32 + j * 16 + m16);
#pragma unroll
        for (int s = 0; s < 2; s++)
            qf[j][s] = *reinterpret_cast<const bf16x8*>(
                &qb[tok * EMBED + h * DQ + s * 32 + kq * 8]);
    }

    f32x4 o[4][2];   // o[mt][j]: O^T tile (d = mt*16+kq*4+reg, qcol = j*16+m16)
    f32x4 o4[2];     // l accumulator (all regs equal per lane)
#pragma unroll
    for (int j = 0; j < 2; j++) {
        o4[j] = f32x4{0.f, 0.f, 0.f, 0.f};
#pragma unroll
        for (int mt = 0; mt < 4; mt++) o[mt][j] = f32x4{0.f, 0.f, 0.f, 0.f};
    }

    asm volatile("s_waitcnt vmcnt(0)" ::: "memory");   // tile 0 + Q landed
    __builtin_amdgcn_s_barrier();
    asm volatile("" ::: "memory");

    const int NT = LSEQ / 64;    // 32
    for (int kt = 0; kt < NT; kt++) {
        const int cur = kt & 1;
        if (kt + 1 < NT) stage(cur ^ 1);   // prefetch next tile (no wait)

        // St = K @ Q^T : st[i][j], key = i*16+kq*4+reg, qcol = j*16+m16
        f32x4 st[4][2];
#pragma unroll
        for (int i = 0; i < 4; i++)
#pragma unroll
            for (int j = 0; j < 2; j++) st[i][j] = f32x4{0.f, 0.f, 0.f, 0.f};

#pragma unroll
        for (int s = 0; s < 2; s++) {
            bf16x8 ak[4];
#pragma unroll
            for (int i = 0; i < 4; i++) {
                int key = i * 16 + m16;
                ak[i] = *reinterpret_cast<const bf16x8*>(
                    &Ks[cur][key * 64 + (((s * 4 + kq) ^ (m16 & 7)) * 8)]);
            }
            __builtin_amdgcn_s_setprio(1);
#pragma unroll
            for (int i = 0; i < 4; i++)
#pragma unroll
                for (int j = 0; j < 2; j++)
                    st[i][j] = __builtin_amdgcn_mfma_f32_16x16x32_bf16(ak[i], qf[j][s], st[i][j], 0, 0, 0);
            __builtin_amdgcn_s_setprio(0);
        }

        // PV over two 32-key chunks t. V^T fragment: one b128 per (t,mt)
        // (vtbuf keys pre-permuted to the K=32 slot map k=8kq+e).
        // P fragment: pb[j] slots e<4 = st[2t][j][e], e>=4 = st[2t+1][j][e-4].
#pragma unroll
        for (int t = 0; t < 2; t++) {
            bf16x8 av8[4];
#pragma unroll
            for (int mt = 0; mt < 4; mt++) {
                int d = mt * 16 + m16;
                av8[mt] = *reinterpret_cast<const bf16x8*>(
                    &Vt[cur][d * 64 + (((t * 4 + kq) ^ (m16 & 7)) * 8)]);
            }
            // p = exp2(st) for key-blocks 2t, 2t+1 (Q pre-scaled)
#pragma unroll
            for (int ii = 0; ii < 2; ii++)
#pragma unroll
                for (int j = 0; j < 2; j++)
#pragma unroll
                    for (int q = 0; q < 4; q++)
                        st[2 * t + ii][j][q] = __builtin_amdgcn_exp2f(st[2 * t + ii][j][q]);
            bf16x8 pb[2];
#pragma unroll
            for (int j = 0; j < 2; j++) {
                uint4 pu;
                pu.x = pack2t(st[2 * t][j][0],     st[2 * t][j][1]);
                pu.y = pack2t(st[2 * t][j][2],     st[2 * t][j][3]);
                pu.z = pack2t(st[2 * t + 1][j][0], st[2 * t + 1][j][1]);
                pu.w = pack2t(st[2 * t + 1][j][2], st[2 * t + 1][j][3]);
                pb[j] = __builtin_bit_cast(bf16x8, pu);
            }
            __builtin_amdgcn_s_setprio(1);
#pragma unroll
            for (int mt = 0; mt < 4; mt++)
#pragma unroll
                for (int j = 0; j < 2; j++)
                    o[mt][j] = __builtin_amdgcn_mfma_f32_16x16x32_bf16(av8[mt], pb[j], o[mt][j], 0, 0, 0);
#pragma unroll
            for (int j = 0; j < 2; j++)
                o4[j] = __builtin_amdgcn_mfma_f32_16x16x32_bf16(ones8, pb[j], o4[j], 0, 0, 0);
            __builtin_amdgcn_s_setprio(0);
        }

        // Release buf[cur] for next iter's stage; next tile's loads (issued
        // at iter top) drained here, hidden under the compute above.
        if (kt + 1 < NT) {
            asm volatile("s_waitcnt vmcnt(0)" ::: "memory");
            __builtin_amdgcn_s_barrier();
            asm volatile("" ::: "memory");
        }
    }

    // Epilogue: normalize by l (= o4[j][0], identical in all regs), write ao.
#pragma unroll
    for (int j = 0; j < 2; j++) {
        float inv = 1.f / o4[j][0];
        size_t tok = (size_t)(nn * LSEQ + q0 + wave * 32 + j * 16 + m16);
#pragma unroll
        for (int mt = 0; mt < 4; mt++) {
            *reinterpret_cast<uint2*>(&ao[tok * EMBED + h * DQ + mt * 16 + kq * 4]) =
                pack4(o[mt][j][0] * inv, o[mt][j][1] * inv, o[mt][j][2] * inv, o[mt][j][3] * inv);
        }
    }
}

// ---------------- host ----------------
extern "C" void kernel_launch(void* const* d_in, const int* in_sizes, int n_in,
                              void* d_out, int out_size, void* d_ws, size_t ws_size,
                              hipStream_t stream) {
    (void)in_sizes; (void)n_in; (void)out_size; (void)ws_size;
    const float* x     = (const float*)d_in[0];
    const float* W_q   = (const float*)d_in[1];
    const float* W_k   = (const float*)d_in[2];
    const float* W_v   = (const float*)d_in[3];
    const float* W_qp  = (const float*)d_in[4];
    const float* W_kp  = (const float*)d_in[5];
    const float* W_vp  = (const float*)d_in[6];
    const float* W_out = (const float*)d_in[7];

    unsigned short* ws16 = (unsigned short*)d_ws;
    const size_t SZX = (size_t)MROWS * EMBED;   // 8,388,608
    const size_t SZW = (size_t)EMBED * EMBED;   // 1,048,576

    unsigned short* xb    = ws16;
    unsigned short* wqpb  = xb + SZX;
    unsigned short* wkpb  = wqpb + SZW;
    unsigned short* wvpb  = wkpb + SZW;
    unsigned short* woutb = wvpb + SZW;
    unsigned short* wqT   = woutb + SZW;        // transposed bf16 first-layer weights
    unsigned short* wkT   = wqT + SZW;
    unsigned short* wvT   = wkT + SZW;
    unsigned short* weq   = wvT + SZW;          // fused W_eff = W_p @ W
    unsigned short* wek   = weq + SZW;
    unsigned short* wev   = wek + SZW;
    unsigned short* qbuf  = wev + SZW;
    unsigned short* kbuf  = qbuf + SZX;
    unsigned short* vtbuf = kbuf + SZX;
    unsigned short* ao    = vtbuf + SZX;
    // total: 5*SZX + 10*SZW shorts ~= 105 MB

    // 1) prep: 3 transposed converts + 4 straight weight converts, one launch
    PrepArgs pa;
    pa.tsrc[0] = W_q;  pa.tsrc[1] = W_k;  pa.tsrc[2] = W_v;
    pa.tdst[0] = wqT;  pa.tdst[1] = wkT;  pa.tdst[2] = wvT;
    pa.csrc[0] = W_qp;  pa.cdst[0] = wqpb;
    pa.csrc[1] = W_kp;  pa.cdst[1] = wkpb;
    pa.csrc[2] = W_vp;  pa.cdst[2] = wvpb;
    pa.csrc[3] = W_out; pa.cdst[3] = woutb;
    prep_all<<<dim3(16, 16, 7), 256, 0, stream>>>(pa);

    // 2) weight fusion W_eff = W_p @ W (n64 tiles, z 0..2) CONCURRENT with
    //    x bf16 cvt (z 3..5).
    FuseXArgs fx;
    fx.g.A[0] = wqpb; fx.g.A[1] = wkpb; fx.g.A[2] = wvpb;
    fx.g.B[0] = wqT;  fx.g.B[1] = wkT;  fx.g.B[2] = wvT;
    fx.g.C[0] = weq;  fx.g.C[1] = wek;  fx.g.C[2] = wev;
    fx.g.mode[0] = 0; fx.g.mode[1] = 0; fx.g.mode[2] = 0;
    fx.g.scl[0] = 1.f; fx.g.scl[1] = 1.f; fx.g.scl[2] = 1.f;
    fx.xsrc = x;
    fx.xdst = xb;
    gemm_fuse_xcvt<<<dim3(16, 8, 6), 256, 0, stream>>>(fx);

    // 3) projections: q = (x@Weq^T)*0.125*log2e, k = x@Wek^T, v^T = (x@Wev^T)^T
    //    (mode 2 writes vtbuf with the 32-key-group permutation for flash PV)
    BGemmArgs pj;
    pj.A[0] = xb;   pj.A[1] = xb;   pj.A[2] = xb;
    pj.B[0] = weq;  pj.B[1] = wek;  pj.B[2] = wev;
    pj.C[0] = qbuf; pj.C[1] = kbuf; pj.C[2] = vtbuf;
    pj.mode[0] = 0; pj.mode[1] = 0; pj.mode[2] = 2;
    pj.scl[0] = 0.18033688f; pj.scl[1] = 1.f; pj.scl[2] = 1.f;
    gemm_bf16nt<<<dim3(8, 64, 3), 256, 0, stream>>>(pj, MROWS, EMBED, EMBED);

    // 4) flash attention
    flash_bf16<<<dim3(LSEQ / 128, NB * NH), 256, 0, stream>>>(qbuf, kbuf, vtbuf, ao);

    // 5) out = ao @ W_out^T (fp32 out) -- n64 tiles: 1024 blocks = 4/CU
    //    (128x128 tiles gave 512 blocks = 2/CU, the R4 27%-MfmaUtil regime).
    BGemmArgs og;
    og.A[0] = ao;    og.A[1] = ao;    og.A[2] = ao;
    og.B[0] = woutb; og.B[1] = woutb; og.B[2] = woutb;
    og.C[0] = d_out; og.C[1] = d_out; og.C[2] = d_out;
    og.mode[0] = 1; og.mode[1] = 1; og.mode[2] = 1;
    og.scl[0] = 1.f; og.scl[1] = 1.f; og.scl[2] = 1.f;
    gemm_n64<<<dim3(16, 64, 1), 256, 0, stream>>>(og, MROWS, EMBED, EMBED);
}